// Round 1
// baseline (616.322 us; speedup 1.0000x reference)
//
#include <hip/hip_runtime.h>
#include <hip/hip_bf16.h>
#include <math.h>

// Problem dims (fixed by reference setup_inputs):
//   x  [B=64, C=28, H=256, W=256] f32
//   W1 [28,28], b1[28], W2[168,28], b2[168]
//   out [64, 6, 28] f32  (Q^T per batch, Q from reduced QR of m^T [28x6])
#define BATCH 64
#define CH    28
#define HW    65536        // 256*256
#define RANK  6
#define OUTC  (RANK*CH)    // 168

// ---------------------------------------------------------------------------
// Kernel 1: global average pool.  One block per (b,c) row; each row is a
// contiguous 65536-float (256 KB) stream -> float4 coalesced loads.
// ---------------------------------------------------------------------------
__global__ __launch_bounds__(256) void pool_kernel(const float* __restrict__ x,
                                                   float* __restrict__ p) {
    const int row = blockIdx.x;  // 0 .. B*C-1
    const float4* __restrict__ src =
        reinterpret_cast<const float4*>(x + (size_t)row * HW);

    float s = 0.0f;
    // HW/4 = 16384 float4 per row; 256 threads -> 64 iters each.
    for (int i = threadIdx.x; i < (HW / 4); i += 256) {
        float4 v = src[i];
        s += (v.x + v.y) + (v.z + v.w);
    }
    // wave64 butterfly reduce
    #pragma unroll
    for (int m = 1; m < 64; m <<= 1) s += __shfl_xor(s, m);

    __shared__ float ws[4];
    const int wid = threadIdx.x >> 6;
    if ((threadIdx.x & 63) == 0) ws[wid] = s;
    __syncthreads();
    if (threadIdx.x == 0) {
        float t = (ws[0] + ws[1]) + (ws[2] + ws[3]);
        p[row] = t * (1.0f / (float)HW);
    }
}

// ---------------------------------------------------------------------------
// Kernel 2: per-batch head.  One block (1 wave, 64 threads) per batch:
//   h = gelu_exact(p @ W1^T + b1)        [28]
//   y = h @ W2^T + b2                    [168]
//   A = reshape(y, [6,28])^T             [28x6]
//   Householder QR (LAPACK dlarfg sign convention) -> Q [28x6]
//   out[b] = Q^T                         [6x28]
// ---------------------------------------------------------------------------
__global__ __launch_bounds__(64) void head_kernel(const float* __restrict__ p,
                                                  const float* __restrict__ W1,
                                                  const float* __restrict__ b1,
                                                  const float* __restrict__ W2,
                                                  const float* __restrict__ b2,
                                                  float* __restrict__ out) {
    const int b    = blockIdx.x;
    const int lane = threadIdx.x;  // 0..63, single wave

    __shared__ float p_s[CH];
    __shared__ float h_s[CH];
    __shared__ float A[CH][RANK];   // input matrix, then v's below diag
    __shared__ float Q[CH][RANK];
    __shared__ float tau_s[RANK];

    if (lane < CH) p_s[lane] = p[b * CH + lane];
    __syncthreads();

    // h = gelu(W1 @ p + b1), exact erf GELU
    if (lane < CH) {
        float z = b1[lane];
        #pragma unroll
        for (int j = 0; j < CH; ++j) z += W1[lane * CH + j] * p_s[j];
        h_s[lane] = 0.5f * z * (1.0f + erff(z * 0.70710678118654752440f));
    }
    __syncthreads();

    // y = W2 @ h + b2, scattered directly into A (A[i][k] = y[k*28+i])
    for (int r = lane; r < OUTC; r += 64) {
        float z = b2[r];
        #pragma unroll
        for (int j = 0; j < CH; ++j) z += W2[r * CH + j] * h_s[j];
        const int k = r / CH;
        const int i = r - k * CH;
        A[i][k] = z;
    }
    __syncthreads();

    // ---- Householder QR of A (28x6), LAPACK convention ----
    #pragma unroll
    for (int k = 0; k < RANK; ++k) {
        // xnorm^2 over strictly-below-diagonal part
        float xv = (lane > k && lane < CH) ? A[lane][k] : 0.0f;
        float ss = xv * xv;
        #pragma unroll
        for (int m = 1; m < 64; m <<= 1) ss += __shfl_xor(ss, m);

        const float alpha = A[k][k];  // uniform broadcast read
        float tau = 0.0f;
        float vlane = 0.0f;
        if (ss != 0.0f) {  // wave-uniform branch
            const float normx = sqrtf(ss + alpha * alpha);
            const float beta  = (alpha >= 0.0f) ? -normx : normx;
            tau = (beta - alpha) / beta;
            const float v0inv = 1.0f / (alpha - beta);
            vlane = (lane == k) ? 1.0f
                   : ((lane > k && lane < CH) ? A[lane][k] * v0inv : 0.0f);
            // apply H = I - tau v v^T to trailing columns
            for (int j = k + 1; j < RANK; ++j) {
                float t = (lane < CH) ? vlane * A[lane][j] : 0.0f;
                #pragma unroll
                for (int m = 1; m < 64; m <<= 1) t += __shfl_xor(t, m);
                const float w = tau * t;
                if (lane >= k && lane < CH) A[lane][j] -= w * vlane;
            }
        }
        if (lane == 0) tau_s[k] = tau;
        // store scaled v below the diagonal for Q back-accumulation
        if (lane > k && lane < CH) A[lane][k] = vlane;
        __syncthreads();
    }

    // ---- form Q = H_0 ... H_5 * I(28x6) (apply H_5 first) ----
    if (lane < CH) {
        #pragma unroll
        for (int j = 0; j < RANK; ++j) Q[lane][j] = (lane == j) ? 1.0f : 0.0f;
    }
    __syncthreads();
    #pragma unroll
    for (int k = RANK - 1; k >= 0; --k) {
        const float tau = tau_s[k];
        const float vlane = (lane == k) ? 1.0f
                           : ((lane > k && lane < CH) ? A[lane][k] : 0.0f);
        #pragma unroll
        for (int j = 0; j < RANK; ++j) {
            float t = (lane < CH) ? vlane * Q[lane][j] : 0.0f;
            #pragma unroll
            for (int m = 1; m < 64; m <<= 1) t += __shfl_xor(t, m);
            const float w = tau * t;  // tau==0 -> no-op (H=I)
            if (lane >= k && lane < CH) Q[lane][j] -= w * vlane;
        }
        __syncthreads();
    }

    // out[b][k][i] = Q[i][k]
    for (int idx = lane; idx < OUTC; idx += 64) {
        const int k = idx / CH;
        const int i = idx - k * CH;
        out[b * OUTC + idx] = Q[i][k];
    }
}

extern "C" void kernel_launch(void* const* d_in, const int* in_sizes, int n_in,
                              void* d_out, int out_size, void* d_ws, size_t ws_size,
                              hipStream_t stream) {
    const float* x  = (const float*)d_in[0];
    const float* W1 = (const float*)d_in[1];
    const float* b1 = (const float*)d_in[2];
    const float* W2 = (const float*)d_in[3];
    const float* b2 = (const float*)d_in[4];
    float* out = (float*)d_out;
    float* p   = (float*)d_ws;   // BATCH*CH floats of scratch

    pool_kernel<<<BATCH * CH, 256, 0, stream>>>(x, p);
    head_kernel<<<BATCH, 64, 0, stream>>>(p, W1, b1, W2, b2, out);
}